// Round 1
// baseline (74.910 us; speedup 1.0000x reference)
//
#include <hip/hip_runtime.h>

#define TILE_W 64
#define TILE_H 64
#define HALO   6
#define LDS_W  76   // 70 rounded up: keeps rows 16B-aligned, reduces bank aliasing

__global__ __launch_bounds__(256, 2)
void conv7x7_kernel(const float* __restrict__ x,
                    const float* __restrict__ w,
                    const float* __restrict__ bias,
                    float* __restrict__ out)
{
    const int N  = 4096;   // input dim
    const int ON = 4090;   // output dim (valid conv)

    __shared__ float tile[TILE_H + HALO][LDS_W];   // 70 x 76 floats = 21.3 KB

    // Weights: uniform address + compile-time indices -> scalar loads / SGPRs.
    float ws[49];
    #pragma unroll
    for (int i = 0; i < 49; ++i) ws[i] = w[i];

    const int tid = threadIdx.x;
    const int x0  = blockIdx.x * TILE_W;
    const int y0  = blockIdx.y * TILE_H;

    // ---- stage 70x70 input tile into LDS (coalesced 64-wide dword loads) ----
    {
        const int lane = tid & 63;
        const int wrow = tid >> 6;                    // 0..3
        const int gx0  = min(x0 + lane,      N - 1);  // clamp: clamped values only
        const int gx1  = min(x0 + lane + 64, N - 1);  // feed guarded outputs
        for (int r = wrow; r < TILE_H + HALO; r += 4) {
            const int gy = min(y0 + r, N - 1);
            const float* src = x + (size_t)gy * N;
            tile[r][lane] = src[gx0];
            if (lane < HALO) tile[r][lane + 64] = src[gx1];
        }
    }
    __syncthreads();

    // ---- each thread computes a 4x4 output micro-tile ----
    const int tx = (tid & 15) * 4;   // 0..60
    const int ty = (tid >> 4) * 4;   // 0..60

    float acc[4][4] = {};

    #pragma unroll
    for (int rr = 0; rr < 10; ++rr) {   // 10 input rows feed 4 output rows
        float v[10];
        const float4 a = *reinterpret_cast<const float4*>(&tile[ty + rr][tx]);
        const float4 b = *reinterpret_cast<const float4*>(&tile[ty + rr][tx + 4]);
        const float2 c = *reinterpret_cast<const float2*>(&tile[ty + rr][tx + 8]);
        v[0] = a.x; v[1] = a.y; v[2] = a.z; v[3] = a.w;
        v[4] = b.x; v[5] = b.y; v[6] = b.z; v[7] = b.w;
        v[8] = c.x; v[9] = c.y;

        #pragma unroll
        for (int r = 0; r < 4; ++r) {
            const int ky = rr - r;                 // compile-time after unroll
            if (ky >= 0 && ky < 7) {
                #pragma unroll
                for (int kx = 0; kx < 7; ++kx) {
                    const float wk = ws[ky * 7 + kx];
                    #pragma unroll
                    for (int j = 0; j < 4; ++j)
                        acc[r][j] = fmaf(v[kx + j], wk, acc[r][j]);
                }
            }
        }
    }

    // ---- store with edge guards ----
    const float bv = bias[0];
    #pragma unroll
    for (int r = 0; r < 4; ++r) {
        const int oy = y0 + ty + r;
        if (oy < ON) {
            float* dst = out + (size_t)oy * ON;
            #pragma unroll
            for (int j = 0; j < 4; ++j) {
                const int ox = x0 + tx + j;
                if (ox < ON) dst[ox] = acc[r][j] + bv;
            }
        }
    }
}

extern "C" void kernel_launch(void* const* d_in, const int* in_sizes, int n_in,
                              void* d_out, int out_size, void* d_ws, size_t ws_size,
                              hipStream_t stream) {
    const float* x    = (const float*)d_in[0];
    const float* w    = (const float*)d_in[1];
    const float* bias = (const float*)d_in[2];
    float* out        = (float*)d_out;

    const int ON = 4090;
    dim3 grid((ON + TILE_W - 1) / TILE_W, (ON + TILE_H - 1) / TILE_H);  // 64 x 64
    conv7x7_kernel<<<grid, dim3(256, 1, 1), 0, stream>>>(x, w, bias, out);
}

// Round 2
// 41.858 us; speedup vs baseline: 1.7896x; 1.7896x over previous
//
#include <hip/hip_runtime.h>

#define TILE_W 128
#define TILE_H 64
#define HALO   6
#define IN_H   (TILE_H + HALO)   // 70 input rows
#define LDS_W  136               // 134 rounded up -> rows stay 16B-aligned
#define N      4096
#define ON     4090

__device__ __forceinline__ void gload_lds4(const float* g, float* l) {
    __builtin_amdgcn_global_load_lds(
        (const __attribute__((address_space(1))) void*)g,
        (__attribute__((address_space(3))) void*)l,
        4, 0, 0);   // 4 bytes per lane, dest = uniform base + lane*4
}

__global__ __launch_bounds__(256, 4)
void conv7x7_kernel(const float* __restrict__ x,
                    const float* __restrict__ w,
                    const float* __restrict__ bias,
                    float* __restrict__ out)
{
    __shared__ float tile[IN_H][LDS_W];   // 70 x 136 x 4B = 38,080 B

    const int tid  = threadIdx.x;
    const int lane = tid & 63;
    const int wv   = tid >> 6;            // wave 0..3
    const int x0   = blockIdx.x * TILE_W; // <= 3968
    const int y0   = blockIdx.y * TILE_H; // <= 4032

    // ---- stage 70 x 134 input tile straight into LDS ----
    // cols x0+lane (<=4031) and x0+64+lane (<=4095) never go OOB; only the
    // third segment needs a clamp (clamped values feed only guarded outputs).
    {
        const int gx2 = min(x0 + 128 + lane, N - 1);
        for (int r = wv; r < IN_H; r += 4) {
            const int gy = min(y0 + r, N - 1);
            const float* rowp = x + (size_t)gy * N;
            gload_lds4(rowp + x0 + lane,      &tile[r][0]);
            gload_lds4(rowp + x0 + 64 + lane, &tile[r][64]);
            if (lane < 8)
                gload_lds4(rowp + gx2,        &tile[r][128]);
        }
    }

    // uniform-address weight/bias loads (scalar path) overlap the staging
    float ws[49];
    #pragma unroll
    for (int i = 0; i < 49; ++i) ws[i] = w[i];
    const float bv = bias[0];

    __syncthreads();   // compiler drains vmcnt(0) before s_barrier

    // ---- each thread computes an 8-wide x 4-tall output micro-tile ----
    const int tx = (tid & 15) * 8;   // 0..120
    const int ty = (tid >> 4) * 4;   // 0..60

    float acc[4][8] = {};

    #pragma unroll
    for (int rr = 0; rr < 10; ++rr) {    // 10 input rows feed 4 output rows
        const float* row = &tile[ty + rr][tx];
        float v[14];
        const float4 a = *reinterpret_cast<const float4*>(row);
        const float4 b = *reinterpret_cast<const float4*>(row + 4);
        const float4 c = *reinterpret_cast<const float4*>(row + 8);
        const float2 d = *reinterpret_cast<const float2*>(row + 12);
        v[0]=a.x;  v[1]=a.y;  v[2]=a.z;  v[3]=a.w;
        v[4]=b.x;  v[5]=b.y;  v[6]=b.z;  v[7]=b.w;
        v[8]=c.x;  v[9]=c.y;  v[10]=c.z; v[11]=c.w;
        v[12]=d.x; v[13]=d.y;

        #pragma unroll
        for (int r = 0; r < 4; ++r) {
            const int ky = rr - r;               // compile-time after unroll
            if (ky >= 0 && ky < 7) {
                #pragma unroll
                for (int kx = 0; kx < 7; ++kx) {
                    const float wk = ws[ky * 7 + kx];
                    #pragma unroll
                    for (int j = 0; j < 8; ++j)
                        acc[r][j] = fmaf(v[kx + j], wk, acc[r][j]);
                }
            }
        }
    }

    // ---- store: unguarded float2 path for interior, guarded for edges ----
    const int ox0 = x0 + tx;
    const int oy0 = y0 + ty;
    if (ox0 + 8 <= ON && oy0 + 4 <= ON) {
        #pragma unroll
        for (int r = 0; r < 4; ++r) {
            float* dst = out + (size_t)(oy0 + r) * ON + ox0;  // 8B-aligned
            #pragma unroll
            for (int j = 0; j < 4; ++j) {
                const float2 t = make_float2(acc[r][2*j] + bv, acc[r][2*j+1] + bv);
                *reinterpret_cast<float2*>(dst + 2*j) = t;
            }
        }
    } else {
        #pragma unroll
        for (int r = 0; r < 4; ++r) {
            const int oy = oy0 + r;
            if (oy < ON) {
                float* dst = out + (size_t)oy * ON;
                #pragma unroll
                for (int j = 0; j < 8; ++j) {
                    const int ox = ox0 + j;
                    if (ox < ON) dst[ox] = acc[r][j] + bv;
                }
            }
        }
    }
}

extern "C" void kernel_launch(void* const* d_in, const int* in_sizes, int n_in,
                              void* d_out, int out_size, void* d_ws, size_t ws_size,
                              hipStream_t stream) {
    const float* x    = (const float*)d_in[0];
    const float* w    = (const float*)d_in[1];
    const float* bias = (const float*)d_in[2];
    float* out        = (float*)d_out;

    dim3 grid((ON + TILE_W - 1) / TILE_W, (ON + TILE_H - 1) / TILE_H);  // 32 x 64
    conv7x7_kernel<<<grid, dim3(256, 1, 1), 0, stream>>>(x, w, bias, out);
}

// Round 3
// 37.137 us; speedup vs baseline: 2.0171x; 1.1271x over previous
//
#include <hip/hip_runtime.h>

#define TILE_W 128
#define TILE_H 64
#define HALO   6
#define IN_H   (TILE_H + HALO)          // 70 input rows
#define LDS_W  136                      // 134 needed, padded (mult of 4)
#define CPR    (LDS_W / 4)              // 34 float4-chunks per row
#define TILE_CHUNKS (IN_H * CPR)        // 2380
#define STAGE_INSTR ((TILE_CHUNKS + 63) / 64)   // 38
#define LDS_FLOATS  (STAGE_INSTR * 64 * 4)      // 9728 (incl. overshoot pad)
#define N  4096
#define ON 4090

__device__ __forceinline__ void gload_lds16(const float* g, float* l) {
    __builtin_amdgcn_global_load_lds(
        (const __attribute__((address_space(1))) void*)g,
        (__attribute__((address_space(3))) void*)l,
        16, 0, 0);   // 16 B per lane, dest = uniform base + lane*16
}

__global__ __launch_bounds__(256, 4)
void conv7x7_kernel(const float* __restrict__ x,
                    const float* __restrict__ w,
                    const float* __restrict__ bias,
                    float* __restrict__ out)
{
    __shared__ float tile[LDS_FLOATS];   // 38,912 B -> 4 blocks/CU

    const int tid  = threadIdx.x;
    const int lane = tid & 63;
    const int wv   = tid >> 6;
    const int x0   = blockIdx.x * TILE_W;
    const int y0   = blockIdx.y * TILE_H;

    // ---- stage 70 x 134(+pad) tile: flat float4-chunk order, 1 KiB/instr ----
    // chunk m -> (row = m/34, colchunk = m%34); LDS offset = 16*m (linear).
    // Row/col clamps only engage on edge blocks; clamped data lands in LDS
    // slots that are never consumed by stored outputs.
    {
        const int xc0 = x0 >> 2;                  // global chunk col base
        for (int k = wv; k < STAGE_INSTR; k += 4) {
            const int m   = (k << 6) + lane;      // tile chunk index
            const int row = m / CPR;              // magic-mul
            const int cc  = m - row * CPR;
            const int gy  = min(y0 + row, N - 1);
            const int gc  = min(xc0 + cc, (N >> 2) - 1);
            const float* src = x + ((size_t)gy << 12) + ((size_t)gc << 2);
            gload_lds16(src, tile + (k << 8));
        }
    }

    // uniform-address weight/bias loads (scalar path) overlap staging
    float ws[49];
    #pragma unroll
    for (int i = 0; i < 49; ++i) ws[i] = w[i];
    const float bv = bias[0];

    __syncthreads();   // drains vmcnt before s_barrier

    // ---- compute: thread = (colchunk tau, rowgroup rg); 4-wide x 8-tall ----
    const int tau   = tid & 31;          // 0..31 -> cols 4*tau .. 4*tau+3
    const int rg    = tid >> 5;          // 0..7  -> rows 8*rg .. 8*rg+7
    const int colf  = tau << 2;
    const int rbase = rg << 3;

    float acc[8][4] = {};

    #pragma unroll
    for (int rr = 0; rr < 14; ++rr) {    // 14 input rows feed 8 output rows
        const float* rp = tile + (rbase + rr) * LDS_W + colf;
        float v[10];
        const float4 a = *reinterpret_cast<const float4*>(rp);
        const float4 b = *reinterpret_cast<const float4*>(rp + 4);
        const float2 c = *reinterpret_cast<const float2*>(rp + 8);
        v[0]=a.x; v[1]=a.y; v[2]=a.z; v[3]=a.w;
        v[4]=b.x; v[5]=b.y; v[6]=b.z; v[7]=b.w;
        v[8]=c.x; v[9]=c.y;

        #pragma unroll
        for (int r = 0; r < 8; ++r) {
            const int ky = rr - r;               // compile-time after unroll
            if (ky >= 0 && ky < 7) {
                #pragma unroll
                for (int kx = 0; kx < 7; ++kx) {
                    const float wk = ws[ky * 7 + kx];
                    #pragma unroll
                    for (int j = 0; j < 4; ++j)
                        acc[r][j] = fmaf(v[kx + j], wk, acc[r][j]);
                }
            }
        }
    }

    // ---- store: unguarded float2 pairs interior, guarded scalar on edges ----
    const int ox  = x0 + colf;
    const int oy0 = y0 + rbase;
    if (ox + 4 <= ON && oy0 + 8 <= ON) {
        #pragma unroll
        for (int r = 0; r < 8; ++r) {
            float* dst = out + (size_t)(oy0 + r) * ON + ox;   // 8B-aligned
            *reinterpret_cast<float2*>(dst)     = make_float2(acc[r][0] + bv, acc[r][1] + bv);
            *reinterpret_cast<float2*>(dst + 2) = make_float2(acc[r][2] + bv, acc[r][3] + bv);
        }
    } else {
        #pragma unroll
        for (int r = 0; r < 8; ++r) {
            const int oy = oy0 + r;
            if (oy < ON) {
                float* dst = out + (size_t)oy * ON;
                #pragma unroll
                for (int j = 0; j < 4; ++j) {
                    const int oxj = ox + j;
                    if (oxj < ON) dst[oxj] = acc[r][j] + bv;
                }
            }
        }
    }
}

extern "C" void kernel_launch(void* const* d_in, const int* in_sizes, int n_in,
                              void* d_out, int out_size, void* d_ws, size_t ws_size,
                              hipStream_t stream) {
    const float* x    = (const float*)d_in[0];
    const float* w    = (const float*)d_in[1];
    const float* bias = (const float*)d_in[2];
    float* out        = (float*)d_out;

    dim3 grid((ON + TILE_W - 1) / TILE_W, (ON + TILE_H - 1) / TILE_H);  // 32 x 64
    conv7x7_kernel<<<grid, dim3(256, 1, 1), 0, stream>>>(x, w, bias, out);
}

// Round 4
// 35.074 us; speedup vs baseline: 2.1358x; 1.0588x over previous
//
#include <hip/hip_runtime.h>

#define TILE_W 128
#define TILE_H 32
#define HALO   6
#define IN_H   (TILE_H + HALO)          // 38 input rows
#define LDS_W  136                      // 134 needed, padded (mult of 4)
#define CPR    (LDS_W / 4)              // 34 float4-chunks per row
#define TILE_CHUNKS (IN_H * CPR)        // 1292
#define STAGE_INSTR ((TILE_CHUNKS + 63) / 64)   // 21
#define LDS_FLOATS  (STAGE_INSTR * 64 * 4)      // 5376 floats = 21504 B
#define N  4096
#define ON 4090

__device__ __forceinline__ void gload_lds16(const float* g, float* l) {
    __builtin_amdgcn_global_load_lds(
        (const __attribute__((address_space(1))) void*)g,
        (__attribute__((address_space(3))) void*)l,
        16, 0, 0);   // 16 B per lane, dest = uniform base + lane*16
}

__global__ __launch_bounds__(256, 7)
void conv7x7_kernel(const float* __restrict__ x,
                    const float* __restrict__ w,
                    const float* __restrict__ bias,
                    float* __restrict__ out)
{
    __shared__ float tile[LDS_FLOATS];   // 21,504 B -> 7 blocks/CU

    const int tid  = threadIdx.x;
    const int lane = tid & 63;
    const int wv   = tid >> 6;
    const int x0   = blockIdx.x * TILE_W;
    const int y0   = blockIdx.y * TILE_H;

    // ---- stage 38 x 134(+pad) tile: flat float4-chunk order, 1 KiB/instr ----
    // chunk m -> (row = m/34, colchunk = m%34); LDS dest = 16*m (linear).
    // Clamps only engage on edge blocks / overshoot chunks; clamped data
    // lands in LDS slots never consumed by stored outputs.
    {
        const int xc0 = x0 >> 2;                  // global chunk col base
        for (int k = wv; k < STAGE_INSTR; k += 4) {
            const int m   = (k << 6) + lane;      // tile chunk index
            const int row = m / CPR;              // magic-mul
            const int cc  = m - row * CPR;
            const int gy  = min(y0 + row, N - 1);
            const int gc  = min(xc0 + cc, (N >> 2) - 1);
            const float* src = x + ((size_t)gy << 12) + ((size_t)gc << 2);
            gload_lds16(src, tile + (k << 8));
        }
    }

    // uniform-address weight/bias loads (scalar path) overlap staging
    float ws[49];
    #pragma unroll
    for (int i = 0; i < 49; ++i) ws[i] = w[i];
    const float bv = bias[0];

    __syncthreads();   // drains vmcnt before s_barrier

    // ---- compute: thread = (colchunk tau, rowgroup rg); 4-wide x 4-tall ----
    const int tau   = tid & 31;          // 0..31 -> cols 4*tau .. 4*tau+3
    const int rg    = tid >> 5;          // 0..7  -> rows 4*rg .. 4*rg+3
    const int colf  = tau << 2;
    const int rbase = rg << 2;

    float acc[4][4] = {};

    #pragma unroll
    for (int rr = 0; rr < 10; ++rr) {    // 10 input rows feed 4 output rows
        const float* rp = tile + (rbase + rr) * LDS_W + colf;
        float v[10];
        const float4 a = *reinterpret_cast<const float4*>(rp);
        const float4 b = *reinterpret_cast<const float4*>(rp + 4);
        const float2 c = *reinterpret_cast<const float2*>(rp + 8);
        v[0]=a.x; v[1]=a.y; v[2]=a.z; v[3]=a.w;
        v[4]=b.x; v[5]=b.y; v[6]=b.z; v[7]=b.w;
        v[8]=c.x; v[9]=c.y;

        #pragma unroll
        for (int r = 0; r < 4; ++r) {
            const int ky = rr - r;               // compile-time after unroll
            if (ky >= 0 && ky < 7) {
                #pragma unroll
                for (int kx = 0; kx < 7; ++kx) {
                    const float wk = ws[ky * 7 + kx];
                    #pragma unroll
                    for (int j = 0; j < 4; ++j)
                        acc[r][j] = fmaf(v[kx + j], wk, acc[r][j]);
                }
            }
        }
    }

    // ---- store: unguarded float2 pairs interior, guarded scalar on edges ----
    const int ox  = x0 + colf;
    const int oy0 = y0 + rbase;
    if (ox + 4 <= ON && oy0 + 4 <= ON) {
        #pragma unroll
        for (int r = 0; r < 4; ++r) {
            float* dst = out + (size_t)(oy0 + r) * ON + ox;   // 8B-aligned
            *reinterpret_cast<float2*>(dst)     = make_float2(acc[r][0] + bv, acc[r][1] + bv);
            *reinterpret_cast<float2*>(dst + 2) = make_float2(acc[r][2] + bv, acc[r][3] + bv);
        }
    } else {
        #pragma unroll
        for (int r = 0; r < 4; ++r) {
            const int oy = oy0 + r;
            if (oy < ON) {
                float* dst = out + (size_t)oy * ON;
                #pragma unroll
                for (int j = 0; j < 4; ++j) {
                    const int oxj = ox + j;
                    if (oxj < ON) dst[oxj] = acc[r][j] + bv;
                }
            }
        }
    }
}

extern "C" void kernel_launch(void* const* d_in, const int* in_sizes, int n_in,
                              void* d_out, int out_size, void* d_ws, size_t ws_size,
                              hipStream_t stream) {
    const float* x    = (const float*)d_in[0];
    const float* w    = (const float*)d_in[1];
    const float* bias = (const float*)d_in[2];
    float* out        = (float*)d_out;

    dim3 grid((ON + TILE_W - 1) / TILE_W, (ON + TILE_H - 1) / TILE_H);  // 32 x 128
    conv7x7_kernel<<<grid, dim3(256, 1, 1), 0, stream>>>(x, w, bias, out);
}

// Round 6
// 34.937 us; speedup vs baseline: 2.1442x; 1.0039x over previous
//
#include <hip/hip_runtime.h>

#define TILE_W 128
#define TILE_H 32
#define HALO   6
#define IN_H   (TILE_H + HALO)          // 38 input rows
#define LDS_W  136                      // 134 needed, padded (mult of 4)
#define CPR    (LDS_W / 4)              // 34 float4-chunks per row
#define TILE_CHUNKS (IN_H * CPR)        // 1292
#define STAGE_INSTR ((TILE_CHUNKS + 63) / 64)   // 21
#define LDS_FLOATS  (STAGE_INSTR * 64 * 4)      // 5376 floats = 21504 B
#define N  4096
#define ON 4090

typedef float f32x2 __attribute__((ext_vector_type(2)));   // native vec for nt-store

__device__ __forceinline__ void gload_lds16(const float* g, float* l) {
    __builtin_amdgcn_global_load_lds(
        (const __attribute__((address_space(1))) void*)g,
        (__attribute__((address_space(3))) void*)l,
        16, 0, 0);   // 16 B per lane, dest = uniform base + lane*16
}

__global__ __launch_bounds__(256, 7)
void conv7x7_kernel(const float* __restrict__ x,
                    const float* __restrict__ w,
                    const float* __restrict__ bias,
                    float* __restrict__ out)
{
    __shared__ float tile[LDS_FLOATS];   // 21,504 B -> 7 blocks/CU

    const int tid  = threadIdx.x;
    const int lane = tid & 63;
    const int wv   = tid >> 6;
    const int x0   = blockIdx.x * TILE_W;
    const int y0   = blockIdx.y * TILE_H;

    // ---- stage 38 x 134(+pad) tile: flat float4-chunk order, 1 KiB/instr ----
    {
        const int xc0 = x0 >> 2;                  // global chunk col base
        for (int k = wv; k < STAGE_INSTR; k += 4) {
            const int m   = (k << 6) + lane;      // tile chunk index
            const int row = m / CPR;              // magic-mul
            const int cc  = m - row * CPR;
            const int gy  = min(y0 + row, N - 1);
            const int gc  = min(xc0 + cc, (N >> 2) - 1);
            const float* src = x + ((size_t)gy << 12) + ((size_t)gc << 2);
            gload_lds16(src, tile + (k << 8));
        }
    }

    // uniform-address weight/bias loads (scalar path) overlap staging
    float ws[49];
    #pragma unroll
    for (int i = 0; i < 49; ++i) ws[i] = w[i];
    const float bv = bias[0];

    __syncthreads();   // drains vmcnt before s_barrier

    // ---- compute: thread = (colchunk tau, rowgroup rg); 4-wide x 4-tall ----
    const int tau   = tid & 31;          // 0..31 -> cols 4*tau .. 4*tau+3
    const int rg    = tid >> 5;          // 0..7  -> rows 4*rg .. 4*rg+3
    const int colf  = tau << 2;
    const int rbase = rg << 2;

    float acc[4][4] = {};

    #pragma unroll
    for (int rr = 0; rr < 10; ++rr) {    // 10 input rows feed 4 output rows
        const float* rp = tile + (rbase + rr) * LDS_W + colf;
        float v[10];
        const float4 a = *reinterpret_cast<const float4*>(rp);
        const float4 b = *reinterpret_cast<const float4*>(rp + 4);
        const float2 c = *reinterpret_cast<const float2*>(rp + 8);
        v[0]=a.x; v[1]=a.y; v[2]=a.z; v[3]=a.w;
        v[4]=b.x; v[5]=b.y; v[6]=b.z; v[7]=b.w;
        v[8]=c.x; v[9]=c.y;

        #pragma unroll
        for (int r = 0; r < 4; ++r) {
            const int ky = rr - r;               // compile-time after unroll
            if (ky >= 0 && ky < 7) {
                #pragma unroll
                for (int kx = 0; kx < 7; ++kx) {
                    const float wk = ws[ky * 7 + kx];
                    #pragma unroll
                    for (int j = 0; j < 4; ++j)
                        acc[r][j] = fmaf(v[kx + j], wk, acc[r][j]);
                }
            }
        }
    }

    // ---- store: NON-TEMPORAL (evict-first) — output is write-once, never
    // read; keeping it out of L2/L3 preserves the L3-resident input x ----
    const int ox  = x0 + colf;
    const int oy0 = y0 + rbase;
    if (ox + 4 <= ON && oy0 + 4 <= ON) {
        #pragma unroll
        for (int r = 0; r < 4; ++r) {
            float* dst = out + (size_t)(oy0 + r) * ON + ox;   // 8B-aligned
            f32x2 t0; t0.x = acc[r][0] + bv; t0.y = acc[r][1] + bv;
            f32x2 t1; t1.x = acc[r][2] + bv; t1.y = acc[r][3] + bv;
            __builtin_nontemporal_store(t0, reinterpret_cast<f32x2*>(dst));
            __builtin_nontemporal_store(t1, reinterpret_cast<f32x2*>(dst + 2));
        }
    } else {
        #pragma unroll
        for (int r = 0; r < 4; ++r) {
            const int oy = oy0 + r;
            if (oy < ON) {
                float* dst = out + (size_t)oy * ON;
                #pragma unroll
                for (int j = 0; j < 4; ++j) {
                    const int oxj = ox + j;
                    if (oxj < ON)
                        __builtin_nontemporal_store(acc[r][j] + bv, dst + oxj);
                }
            }
        }
    }
}

extern "C" void kernel_launch(void* const* d_in, const int* in_sizes, int n_in,
                              void* d_out, int out_size, void* d_ws, size_t ws_size,
                              hipStream_t stream) {
    const float* x    = (const float*)d_in[0];
    const float* w    = (const float*)d_in[1];
    const float* bias = (const float*)d_in[2];
    float* out        = (float*)d_out;

    dim3 grid((ON + TILE_W - 1) / TILE_W, (ON + TILE_H - 1) / TILE_H);  // 32 x 128
    conv7x7_kernel<<<grid, dim3(256, 1, 1), 0, stream>>>(x, w, bias, out);
}